// Round 8
// baseline (15.210 us; speedup 1.0000x reference)
//
#include <hip/hip_runtime.h>
#include <stdint.h>

#define B 64
#define N 32
#define K 16
#define NUM_WORDS 65536
#define NBLK 256           // k1 blocks (one per CU)
#define WPB 256            // words per block
#define NTHR 512           // 8 waves per block

typedef unsigned long long u64;

static __device__ __forceinline__ u64 umax64(u64 a, u64 b) { return a > b ? a : b; }

// Kernel 1: lane l = batch l; each wave processes 32 words (wave-uniform cw).
// corr = 4 x 6-bit LDS table lookups (bits 0..23) + 8 sign-xor VALU bits
// (bits 24..31). G packed to scalar regs via ballot (no LDS, no barrier);
// tables built from direct global loads (L1/L2-resident input) -> single
// barrier before the main loop. Per-(block,batch) best key -> ws[b][block].
__global__ __launch_bounds__(NTHR) void mdd_corr(
    const float* __restrict__ noisy,   // [B][N]
    const int* __restrict__ G,         // [K][N]
    const float* __restrict__ sigma2,  // [1]
    u64* __restrict__ ws)              // [B][NBLK]
{
    __shared__ __align__(16) uint32_t cw_lds[WPB];
    __shared__ float T_lds[4 * 64 * 64];       // 64 KB: [g][v][lane]
    __shared__ float bestf_lds[8 * 64];
    __shared__ uint32_t bestw_lds[8 * 64];

    const int tid = threadIdx.x;
    const int l = tid & 63;
    const int wv = tid >> 6;
    const int g = wv & 3;
    const int h = wv >> 2;

    const float scale = -4.0f / sigma2[0];

    // Waves 0-3: pack G rows via ballot (row pair per 256B coalesced load),
    // then compute this wave's 64 codewords. No LDS for g_rows, no barrier.
    if (wv < 4) {
        uint32_t grows[K];
        #pragma unroll
        for (int k = 0; k < K; k += 2) {
            int gv = G[k * N + l];             // rows k,k+1 are contiguous
            u64 m = __ballot(gv & 1);
            grows[k] = (uint32_t)m;            // row k   = lanes 0..31
            grows[k + 1] = (uint32_t)(m >> 32);// row k+1 = lanes 32..63
        }
        uint32_t w = blockIdx.x * WPB + tid;   // tid < 256 here
        uint32_t cw = 0;
        #pragma unroll
        for (int k = 0; k < K; ++k)
            cw ^= grows[k] & (0u - ((w >> k) & 1u));
        cw_lds[tid] = cw;
    }

    // 6-bit tables: T[g][v][l] = sum_{i<6} s((v>>i)&1)*llr[l][6g+i], s(b)=1-2b.
    // Wave wv -> group g = wv&3, half h = wv>>2 (v = h*32 + j), 32 entries/lane.
    // Fixed balanced tree with exact negations: identical cw -> identical bits.
    {
        const float* nb = noisy + l * N + 6 * g;
        float l0 = scale * nb[0];
        float l1 = scale * nb[1];
        float l2 = scale * nb[2];
        float l3 = scale * nb[3];
        float l4 = scale * nb[4];
        float l5 = scale * nb[5];
        float l5s = h ? -l5 : l5;              // bit 5 of v == h
        float P01[4] = { l0 + l1, -l0 + l1, l0 - l1, -l0 - l1 };
        float P23[4] = { l2 + l3, -l2 + l3, l2 - l3, -l2 - l3 };
        float Q0 = l4 + l5s, Q1 = -l4 + l5s;
        float* Tp = &T_lds[g * 4096 + h * 32 * 64 + l];
        #pragma unroll
        for (int j = 0; j < 32; ++j)
            Tp[j * 64] = (P01[j & 3] + P23[(j >> 2) & 3]) + ((j & 16) ? Q1 : Q0);
    }

    // This lane's llr bit-patterns for bits 24..31 (VALU sign-xor path)
    uint32_t lau[8];
    #pragma unroll
    for (int v = 0; v < 8; ++v)
        lau[v] = __float_as_uint(scale * noisy[l * N + 24 + v]);

    __syncthreads();   // single barrier: cw_lds + T_lds ready

    // Main loop: 32 words/thread, strict > with ascending w => first-wins
    const uint4* cw4 = reinterpret_cast<const uint4*>(cw_lds);
    const float* Tl = &T_lds[l];
    float bestf = -INFINITY;
    uint32_t bestw = 0;
    const uint32_t wbase = blockIdx.x * WPB + wv * 32;

    #pragma unroll
    for (int wq = 0; wq < 8; ++wq) {
        uint4 c4 = cw4[wv * 8 + wq];
        #pragma unroll
        for (int e = 0; e < 4; ++e) {
            uint32_t cw = (e == 0) ? c4.x : (e == 1) ? c4.y : (e == 2) ? c4.z : c4.w;
            // LDS pipe: 4 x 6-bit groups (bits 0..23)
            float r0 = Tl[0 * 4096 + ((cw >> 0) & 63u) * 64];
            float r1 = Tl[1 * 4096 + ((cw >> 6) & 63u) * 64];
            float r2 = Tl[2 * 4096 + ((cw >> 12) & 63u) * 64];
            float r3 = Tl[3 * 4096 + ((cw >> 18) & 63u) * 64];
            // VALU pipe: bits 24..31 via sign-bit xor (bit 24+j -> shift 7-j)
            float v0 = __uint_as_float(lau[0] ^ ((cw << 7) & 0x80000000u));
            float v1 = __uint_as_float(lau[1] ^ ((cw << 6) & 0x80000000u));
            float v2 = __uint_as_float(lau[2] ^ ((cw << 5) & 0x80000000u));
            float v3 = __uint_as_float(lau[3] ^ ((cw << 4) & 0x80000000u));
            float v4 = __uint_as_float(lau[4] ^ ((cw << 3) & 0x80000000u));
            float v5 = __uint_as_float(lau[5] ^ ((cw << 2) & 0x80000000u));
            float v6 = __uint_as_float(lau[6] ^ ((cw << 1) & 0x80000000u));
            float v7 = __uint_as_float(lau[7] ^ ((cw << 0) & 0x80000000u));
            float c = ((r0 + r1) + (r2 + r3))
                    + (((v0 + v1) + (v2 + v3)) + ((v4 + v5) + (v6 + v7)));
            uint32_t w = wbase + wq * 4 + e;
            bool gt = c > bestf;
            bestw = gt ? w : bestw;
            bestf = gt ? c : bestf;
        }
    }

    bestf_lds[wv * 64 + l] = bestf;
    bestw_lds[wv * 64 + l] = bestw;
    __syncthreads();

    // Merge 8 waves (ascending w ranges; strict > keeps lower w), store key.
    if (tid < B) {
        float f = bestf_lds[tid];
        uint32_t w = bestw_lds[tid];
        #pragma unroll
        for (int v = 1; v < 8; ++v) {
            float f2 = bestf_lds[v * 64 + tid];
            uint32_t w2 = bestw_lds[v * 64 + tid];
            bool gt = f2 > f;
            w = gt ? w2 : w;
            f = gt ? f2 : f;
        }
        uint32_t bits = __float_as_uint(f);
        uint32_t mono = (bits & 0x80000000u) ? ~bits : (bits | 0x80000000u);
        u64 key = ((u64)mono << 16) | (u64)(0xFFFFu - w);
        ws[(size_t)tid * NBLK + blockIdx.x] = key;
    }
}

// Kernel 2: one wave per batch; fully coalesced 2KB row read; decode bits.
__global__ __launch_bounds__(64) void mdd_out(
    const u64* __restrict__ ws,        // [B][NBLK]
    float* __restrict__ out)           // [B][K]
{
    const int b = blockIdx.x;
    const int t = threadIdx.x;
    const u64* p = ws + (size_t)b * NBLK;

    u64 m = umax64(umax64(p[t], p[t + 64]), umax64(p[t + 128], p[t + 192]));
    #pragma unroll
    for (int off = 32; off > 0; off >>= 1) {
        u64 o = __shfl_xor(m, off, 64);
        m = umax64(m, o);
    }
    uint32_t w = 0xFFFFu - (uint32_t)(m & 0xFFFFull);
    if (t < K) out[b * K + t] = (float)((w >> t) & 1u);
}

extern "C" void kernel_launch(void* const* d_in, const int* in_sizes, int n_in,
                              void* d_out, int out_size, void* d_ws, size_t ws_size,
                              hipStream_t stream) {
    const float* noisy = (const float*)d_in[0];
    const int* G = (const int*)d_in[1];
    const float* sigma2 = (const float*)d_in[2];
    float* out = (float*)d_out;
    u64* ws = (u64*)d_ws;

    (void)in_sizes; (void)n_in; (void)out_size; (void)ws_size;

    mdd_corr<<<NBLK, NTHR, 0, stream>>>(noisy, G, sigma2, ws);
    mdd_out<<<B, 64, 0, stream>>>(ws, out);
}

// Round 9
// 14.702 us; speedup vs baseline: 1.0345x; 1.0345x over previous
//
#include <hip/hip_runtime.h>
#include <stdint.h>

#define B 64
#define N 32
#define K 16
#define NUM_WORDS 65536
#define NBLK 256           // k1 blocks (one per CU)
#define WPB 256            // words per block
#define NTHR 1024          // 16 waves per block -> 4 waves/SIMD
#define LLR_PAD 65         // padded stride for transpose staging

typedef unsigned long long u64;

static __device__ __forceinline__ u64 umax64(u64 a, u64 b) { return a > b ? a : b; }

// Kernel 1: lane l = batch l; each wave processes 16 words (wave-uniform cw).
// corr = 4 x 6-bit LDS table lookups (bits 0..23) + 8 sign-xor VALU bits
// (bits 24..31). 16 waves (4/SIMD) for latency hiding; two independent
// best-accumulators per thread (even/odd words) break the cndmask chain;
// exact merge via packed u64 keys. ws handoff via launch boundary (proven).
__global__ __launch_bounds__(NTHR) void mdd_corr(
    const float* __restrict__ noisy,   // [B][N]
    const int* __restrict__ G,         // [K][N]
    const float* __restrict__ sigma2,  // [1]
    u64* __restrict__ ws)              // [B][NBLK]
{
    __shared__ __align__(16) uint32_t cw_lds[WPB];
    __shared__ float T_lds[4 * 64 * 64];       // 64 KB: [g][v][lane]
    __shared__ float llr_t[N * LLR_PAD];       // [n][b] padded transpose
    __shared__ u64 bestk_lds[16 * 64];         // per-(wave,lane) packed keys

    const int tid = threadIdx.x;
    const int l = tid & 63;
    const int wv = tid >> 6;
    const int g = wv & 3;
    const int q = wv >> 2;

    const float scale = -4.0f / sigma2[0];

    // Coalesced staged transpose: llr_t[n][b] (proved necessary in round 8)
    #pragma unroll
    for (int i = tid; i < B * N; i += NTHR) {
        int n = i & 31, bb = i >> 5;
        llr_t[n * LLR_PAD + bb] = scale * noisy[i];
    }

    // Waves 0-3 concurrently: pack G via ballot (coalesced 256B row-pair
    // loads, no LDS for g_rows) and compute this block's 256 codewords.
    if (wv < 4) {
        uint32_t grows[K];
        #pragma unroll
        for (int k = 0; k < K; k += 2) {
            int gv = G[k * N + l];              // rows k,k+1 contiguous
            u64 m = __ballot(gv & 1);
            grows[k] = (uint32_t)m;
            grows[k + 1] = (uint32_t)(m >> 32);
        }
        uint32_t w = blockIdx.x * WPB + tid;    // tid < 256 here
        uint32_t cw = 0;
        #pragma unroll
        for (int k = 0; k < K; ++k)
            cw ^= grows[k] & (0u - ((w >> k) & 1u));
        cw_lds[tid] = cw;
    }
    __syncthreads();

    // 6-bit tables: T[g][v][l] = sum_{i<6} s((v>>i)&1)*llr[l][6g+i], s(b)=1-2b.
    // Wave wv -> group g, quarter q: entries v = q*16 + j, 16 writes/lane.
    // Each (g,v) entry has exactly one producer with a fixed expression tree
    // -> identical cw always reads identical table bits.
    {
        float l0 = llr_t[(6 * g + 0) * LLR_PAD + l];
        float l1 = llr_t[(6 * g + 1) * LLR_PAD + l];
        float l2 = llr_t[(6 * g + 2) * LLR_PAD + l];
        float l3 = llr_t[(6 * g + 3) * LLR_PAD + l];
        float l4 = llr_t[(6 * g + 4) * LLR_PAD + l];
        float l5 = llr_t[(6 * g + 5) * LLR_PAD + l];
        float l4s = (q & 1) ? -l4 : l4;         // bit 4 of v
        float l5s = (q & 2) ? -l5 : l5;         // bit 5 of v
        float Q = l4s + l5s;
        float P01[4] = { l0 + l1, -l0 + l1, l0 - l1, -l0 - l1 };
        float P23[4] = { l2 + l3, -l2 + l3, l2 - l3, -l2 - l3 };
        float* Tp = &T_lds[g * 4096 + (q * 16) * 64 + l];
        #pragma unroll
        for (int j = 0; j < 16; ++j)
            Tp[j * 64] = (P01[j & 3] + P23[j >> 2]) + Q;
    }

    // This lane's llr bit-patterns for bits 24..31 (VALU sign-xor path)
    uint32_t lau[8];
    #pragma unroll
    for (int v = 0; v < 8; ++v)
        lau[v] = __float_as_uint(llr_t[(24 + v) * LLR_PAD + l]);
    __syncthreads();

    // Main loop: 16 words/thread, even words -> acc A, odd -> acc B.
    // Strict > with ascending w within each stream; exact cross-stream and
    // cross-wave tie resolution via packed keys (higher corr, then lower w).
    const uint4* cw4 = reinterpret_cast<const uint4*>(cw_lds);
    const float* Tl = &T_lds[l];
    float fA = -INFINITY, fB = -INFINITY;
    uint32_t wA = 0, wB = 0;
    const uint32_t wbase = blockIdx.x * WPB + wv * 16;

    #pragma unroll
    for (int wq = 0; wq < 4; ++wq) {
        uint4 c4 = cw4[wv * 4 + wq];
        #pragma unroll
        for (int e = 0; e < 4; ++e) {
            uint32_t cw = (e == 0) ? c4.x : (e == 1) ? c4.y : (e == 2) ? c4.z : c4.w;
            // LDS pipe: 4 x 6-bit groups (bits 0..23)
            float r0 = Tl[0 * 4096 + ((cw >> 0) & 63u) * 64];
            float r1 = Tl[1 * 4096 + ((cw >> 6) & 63u) * 64];
            float r2 = Tl[2 * 4096 + ((cw >> 12) & 63u) * 64];
            float r3 = Tl[3 * 4096 + ((cw >> 18) & 63u) * 64];
            // VALU pipe: bits 24..31 via sign-bit xor
            float v0 = __uint_as_float(lau[0] ^ ((cw << 7) & 0x80000000u));
            float v1 = __uint_as_float(lau[1] ^ ((cw << 6) & 0x80000000u));
            float v2 = __uint_as_float(lau[2] ^ ((cw << 5) & 0x80000000u));
            float v3 = __uint_as_float(lau[3] ^ ((cw << 4) & 0x80000000u));
            float v4 = __uint_as_float(lau[4] ^ ((cw << 3) & 0x80000000u));
            float v5 = __uint_as_float(lau[5] ^ ((cw << 2) & 0x80000000u));
            float v6 = __uint_as_float(lau[6] ^ ((cw << 1) & 0x80000000u));
            float v7 = __uint_as_float(lau[7] ^ ((cw << 0) & 0x80000000u));
            float c = ((r0 + r1) + (r2 + r3))
                    + (((v0 + v1) + (v2 + v3)) + ((v4 + v5) + (v6 + v7)));
            uint32_t w = wbase + wq * 4 + e;
            if ((e & 1) == 0) {
                bool gt = c > fA; wA = gt ? w : wA; fA = gt ? c : fA;
            } else {
                bool gt = c > fB; wB = gt ? w : wB; fB = gt ? c : fB;
            }
        }
    }

    // Pack keys (monotone float map; no NaNs) and merge A/B exactly.
    {
        uint32_t ba = __float_as_uint(fA);
        uint32_t ma = (ba & 0x80000000u) ? ~ba : (ba | 0x80000000u);
        uint32_t bb = __float_as_uint(fB);
        uint32_t mb = (bb & 0x80000000u) ? ~bb : (bb | 0x80000000u);
        u64 kA = ((u64)ma << 16) | (u64)(0xFFFFu - wA);
        u64 kB = ((u64)mb << 16) | (u64)(0xFFFFu - wB);
        bestk_lds[wv * 64 + l] = umax64(kA, kB);
    }
    __syncthreads();

    // Merge 16 waves via u64 max (order-independent), store ws[b][block].
    if (tid < B) {
        u64 m = bestk_lds[tid];
        #pragma unroll
        for (int v = 1; v < 16; ++v)
            m = umax64(m, bestk_lds[v * 64 + tid]);
        ws[(size_t)tid * NBLK + blockIdx.x] = m;
    }
}

// Kernel 2: one wave per batch; fully coalesced 2KB row read; decode bits.
__global__ __launch_bounds__(64) void mdd_out(
    const u64* __restrict__ ws,        // [B][NBLK]
    float* __restrict__ out)           // [B][K]
{
    const int b = blockIdx.x;
    const int t = threadIdx.x;
    const u64* p = ws + (size_t)b * NBLK;

    u64 m = umax64(umax64(p[t], p[t + 64]), umax64(p[t + 128], p[t + 192]));
    #pragma unroll
    for (int off = 32; off > 0; off >>= 1) {
        u64 o = __shfl_xor(m, off, 64);
        m = umax64(m, o);
    }
    uint32_t w = 0xFFFFu - (uint32_t)(m & 0xFFFFull);
    if (t < K) out[b * K + t] = (float)((w >> t) & 1u);
}

extern "C" void kernel_launch(void* const* d_in, const int* in_sizes, int n_in,
                              void* d_out, int out_size, void* d_ws, size_t ws_size,
                              hipStream_t stream) {
    const float* noisy = (const float*)d_in[0];
    const int* G = (const int*)d_in[1];
    const float* sigma2 = (const float*)d_in[2];
    float* out = (float*)d_out;
    u64* ws = (u64*)d_ws;

    (void)in_sizes; (void)n_in; (void)out_size; (void)ws_size;

    mdd_corr<<<NBLK, NTHR, 0, stream>>>(noisy, G, sigma2, ws);
    mdd_out<<<B, 64, 0, stream>>>(ws, out);
}

// Round 10
// 13.519 us; speedup vs baseline: 1.1251x; 1.0875x over previous
//
#include <hip/hip_runtime.h>
#include <stdint.h>

#define B 64
#define N 32
#define K 16
#define NUM_WORDS 65536
#define NBLK 256           // k1 blocks (one per CU)
#define WPB 256            // words per block
#define NTHR 512           // 8 waves per block
#define LLR_PAD 65         // padded stride for transpose staging

typedef unsigned long long u64;

static __device__ __forceinline__ u64 umax64(u64 a, u64 b) { return a > b ? a : b; }

// Kernel 1: lane l = batch l; each wave processes 32 words (wave-uniform cw).
// corr = 4 x 7-bit LDS table lookups (bits 0..27) + 4 sign-xor VALU bits
// (bits 28..31). Per-(block,batch) best key -> plain store to ws[b][block].
// Cross-kernel visibility via the launch boundary (validated rounds 2/3/7).
__global__ __launch_bounds__(NTHR) void mdd_corr(
    const float* __restrict__ noisy,   // [B][N]
    const int* __restrict__ G,         // [K][N]
    const float* __restrict__ sigma2,  // [1]
    u64* __restrict__ ws)              // [B][NBLK]
{
    __shared__ uint32_t g_rows[K];
    __shared__ __align__(16) uint32_t cw_lds[WPB];
    __shared__ float T_lds[4 * 128 * 64];      // 128 KB: [g][v][lane]
    __shared__ float llr_t[N * LLR_PAD];       // [n][b] padded
    __shared__ float bestf_lds[8 * 64];
    __shared__ uint32_t bestw_lds[8 * 64];

    const int tid = threadIdx.x;
    const int l = tid & 63;
    const int wv = tid >> 6;

    // Pack G rows into 32-bit masks (bit n = G[k][n] & 1)
    if (tid < K) {
        const int4* G4 = reinterpret_cast<const int4*>(G) + tid * 8;
        uint32_t r = 0;
        #pragma unroll
        for (int m = 0; m < 8; ++m) {
            int4 gv = G4[m];
            r |= (uint32_t)(gv.x & 1) << (4 * m + 0);
            r |= (uint32_t)(gv.y & 1) << (4 * m + 1);
            r |= (uint32_t)(gv.z & 1) << (4 * m + 2);
            r |= (uint32_t)(gv.w & 1) << (4 * m + 3);
        }
        g_rows[tid] = r;
    }

    // Coalesced load of noisy, transposed into padded LDS: llr_t[n][b]
    const float scale = -4.0f / sigma2[0];
    for (int i = tid; i < B * N; i += NTHR) {
        int n = i & 31, bb = i >> 5;
        llr_t[n * LLR_PAD + bb] = scale * noisy[i];
    }
    __syncthreads();

    // Codewords for this block's 256 words
    if (tid < WPB) {
        uint32_t w = blockIdx.x * WPB + tid;
        uint32_t cw = 0;
        #pragma unroll
        for (int k = 0; k < K; ++k)
            cw ^= g_rows[k] & (0u - ((w >> k) & 1u));
        cw_lds[tid] = cw;
    }

    // 7-bit tables: T[g][v][l] = sum_{i<7} s((v>>i)&1)*llr[l][7g+i], s(b)=1-2b.
    // Team: wave wv -> group g = wv&3, half h = wv>>2 (v = h*64 + j).
    // Balanced exactly-negated trees, compile-time indices only (no scratch).
    {
        const int g = wv & 3, h = wv >> 2;
        float l0 = llr_t[(7 * g + 0) * LLR_PAD + l];
        float l1 = llr_t[(7 * g + 1) * LLR_PAD + l];
        float l2 = llr_t[(7 * g + 2) * LLR_PAD + l];
        float l3 = llr_t[(7 * g + 3) * LLR_PAD + l];
        float l4 = llr_t[(7 * g + 4) * LLR_PAD + l];
        float l5 = llr_t[(7 * g + 5) * LLR_PAD + l];
        float l6 = llr_t[(7 * g + 6) * LLR_PAD + l];
        float l6s = h ? -l6 : l6;                  // bit 6 of v == h
        float P[4] = { l0 + l1, -l0 + l1, l0 - l1, -l0 - l1 };
        float A[8];
        #pragma unroll
        for (int a = 0; a < 8; ++a)
            A[a] = (a & 4) ? (P[a & 3] - l2) : (P[a & 3] + l2);
        float Q[4] = { l3 + l4, -l3 + l4, l3 - l4, -l3 - l4 };
        float R[8];
        #pragma unroll
        for (int r = 0; r < 8; ++r)
            R[r] = (r & 4) ? (Q[r & 3] - l5) : (Q[r & 3] + l5);
        float Cp[8];
        #pragma unroll
        for (int c = 0; c < 8; ++c)
            Cp[c] = R[c] + l6s;
        float* Tg = &T_lds[g * 8192 + h * 64 * 64 + l];
        #pragma unroll
        for (int j = 0; j < 64; ++j)
            Tg[j * 64] = A[j & 7] + Cp[j >> 3];
    }

    // This lane's llr bit-patterns for bits 28..31 (VALU sign-xor path)
    uint32_t lau0 = __float_as_uint(llr_t[28 * LLR_PAD + l]);
    uint32_t lau1 = __float_as_uint(llr_t[29 * LLR_PAD + l]);
    uint32_t lau2 = __float_as_uint(llr_t[30 * LLR_PAD + l]);
    uint32_t lau3 = __float_as_uint(llr_t[31 * LLR_PAD + l]);
    __syncthreads();

    // Main loop: 32 words/thread, strict > with ascending w => first-wins
    const uint4* cw4 = reinterpret_cast<const uint4*>(cw_lds);
    const float* Tl = &T_lds[l];
    float bestf = -INFINITY;
    uint32_t bestw = 0;
    const uint32_t wbase = blockIdx.x * WPB + wv * 32;

    #pragma unroll
    for (int wq = 0; wq < 8; ++wq) {
        uint4 c4 = cw4[wv * 8 + wq];
        #pragma unroll
        for (int e = 0; e < 4; ++e) {
            uint32_t cw = (e == 0) ? c4.x : (e == 1) ? c4.y : (e == 2) ? c4.z : c4.w;
            // LDS pipe: 4 x 7-bit groups
            float r0 = Tl[0 * 8192 + ((cw >> 0) & 127u) * 64];
            float r1 = Tl[1 * 8192 + ((cw >> 7) & 127u) * 64];
            float r2 = Tl[2 * 8192 + ((cw >> 14) & 127u) * 64];
            float r3 = Tl[3 * 8192 + ((cw >> 21) & 127u) * 64];
            // VALU pipe: bits 28..31 via sign-bit xor (fixed order)
            float v0 = __uint_as_float(lau0 ^ ((cw << 3) & 0x80000000u));
            float v1 = __uint_as_float(lau1 ^ ((cw << 2) & 0x80000000u));
            float v2 = __uint_as_float(lau2 ^ ((cw << 1) & 0x80000000u));
            float v3 = __uint_as_float(lau3 ^ ((cw << 0) & 0x80000000u));
            float c = ((r0 + r1) + (r2 + r3)) + ((v0 + v1) + (v2 + v3));
            uint32_t w = wbase + wq * 4 + e;
            bool g = c > bestf;
            bestw = g ? w : bestw;
            bestf = g ? c : bestf;
        }
    }

    bestf_lds[wv * 64 + l] = bestf;
    bestw_lds[wv * 64 + l] = bestw;
    __syncthreads();

    // Merge 8 waves (ascending w ranges; strict > keeps lower w), store key.
    if (tid < B) {
        float f = bestf_lds[tid];
        uint32_t w = bestw_lds[tid];
        #pragma unroll
        for (int v = 1; v < 8; ++v) {
            float f2 = bestf_lds[v * 64 + tid];
            uint32_t w2 = bestw_lds[v * 64 + tid];
            bool g = f2 > f;
            w = g ? w2 : w;
            f = g ? f2 : f;
        }
        uint32_t bits = __float_as_uint(f);
        uint32_t mono = (bits & 0x80000000u) ? ~bits : (bits | 0x80000000u);
        u64 key = ((u64)mono << 16) | (u64)(0xFFFFu - w);
        ws[(size_t)tid * NBLK + blockIdx.x] = key;
    }
}

// Kernel 2: one wave per batch; fully coalesced 2KB row read; decode bits.
__global__ __launch_bounds__(64) void mdd_out(
    const u64* __restrict__ ws,        // [B][NBLK]
    float* __restrict__ out)           // [B][K]
{
    const int b = blockIdx.x;
    const int t = threadIdx.x;
    const u64* p = ws + (size_t)b * NBLK;

    u64 m = umax64(umax64(p[t], p[t + 64]), umax64(p[t + 128], p[t + 192]));
    #pragma unroll
    for (int off = 32; off > 0; off >>= 1) {
        u64 o = __shfl_xor(m, off, 64);
        m = umax64(m, o);
    }
    uint32_t w = 0xFFFFu - (uint32_t)(m & 0xFFFFull);
    if (t < K) out[b * K + t] = (float)((w >> t) & 1u);
}

extern "C" void kernel_launch(void* const* d_in, const int* in_sizes, int n_in,
                              void* d_out, int out_size, void* d_ws, size_t ws_size,
                              hipStream_t stream) {
    const float* noisy = (const float*)d_in[0];
    const int* G = (const int*)d_in[1];
    const float* sigma2 = (const float*)d_in[2];
    float* out = (float*)d_out;
    u64* ws = (u64*)d_ws;

    (void)in_sizes; (void)n_in; (void)out_size; (void)ws_size;

    mdd_corr<<<NBLK, NTHR, 0, stream>>>(noisy, G, sigma2, ws);
    mdd_out<<<B, 64, 0, stream>>>(ws, out);
}